// Round 1
// baseline (973.034 us; speedup 1.0000x reference)
//
#include <hip/hip_runtime.h>
#include <math.h>

#define NPTS 32768
#define NB 2
#define KNB 16
#define CIN 32
#define H 32
#define D 64
#define DOUT 128
#define PPB 4   // points per block in k2/k3 (4 waves of 64)

__device__ __forceinline__ float bnS(float g) { return g * rsqrtf(1.0f + 1e-5f); }

// ---------------- Kernel 1: f_pc = relu(bn(w_mlp1 @ feature)) ----------------
// feature: (B,32,N) channel-major. f_pc out: point-major (B*N, 32).
__global__ __launch_bounds__(256) void k1_mlp1(
    const float* __restrict__ feature, const float* __restrict__ w_mlp1,
    const float* __restrict__ g_mlp1, const float* __restrict__ b_mlp1,
    float* __restrict__ f_pc)
{
    __shared__ __align__(16) float wf[CIN * CIN];
    __shared__ float bf[CIN];
    int tid = threadIdx.x;
    for (int i = tid; i < CIN * CIN; i += 256) {
        int o = i >> 5;
        wf[i] = w_mlp1[i] * bnS(g_mlp1[o]);
    }
    if (tid < CIN) bf[tid] = b_mlp1[tid];
    __syncthreads();

    int pg = blockIdx.x * 256 + tid;
    int b = pg >> 15, n = pg & (NPTS - 1);

    float x[CIN];
#pragma unroll
    for (int c = 0; c < CIN; ++c)
        x[c] = feature[((b * CIN + c) << 15) + n];

    float out[CIN];
#pragma unroll
    for (int o = 0; o < CIN; ++o) {
        float acc = bf[o];
#pragma unroll
        for (int cb = 0; cb < CIN / 4; ++cb) {
            const float4 w4 = *(const float4*)&wf[o * CIN + 4 * cb];
            acc += w4.x * x[4 * cb] + w4.y * x[4 * cb + 1] + w4.z * x[4 * cb + 2] + w4.w * x[4 * cb + 3];
        }
        out[o] = fmaxf(acc, 0.0f);
    }
    float4* dst = (float4*)(f_pc + (size_t)pg * CIN);
#pragma unroll
    for (int j = 0; j < CIN / 4; ++j)
        dst[j] = make_float4(out[4 * j], out[4 * j + 1], out[4 * j + 2], out[4 * j + 3]);
}

// ---------------- Kernel 2: stage-1 building block -> f_agg (B*N, 32) ----------------
__global__ __launch_bounds__(256) void k2_stage1(
    const float* __restrict__ xyz, const int* __restrict__ nidx,
    const float* __restrict__ f_pc,
    const float* __restrict__ bb_w1, const float* __restrict__ bb_g1, const float* __restrict__ bb_b1,
    const float* __restrict__ att_fc,
    const float* __restrict__ att_w, const float* __restrict__ att_g, const float* __restrict__ att_b,
    float* __restrict__ f_agg)
{
    __shared__ float fcT[D * D];                    // [cin][cout]
    __shared__ float w1f[H * 10];
    __shared__ float b1f[H];
    __shared__ float awT[D * H];                    // [c][o], bn-folded
    __shared__ float ab[H];
    __shared__ __align__(16) float feat[PPB][D][20]; // [point][channel][k], padded
    __shared__ float aggbuf[PPB][D];

    int tid = threadIdx.x;
    for (int i = tid; i < D * D; i += 256) {
        int o = i >> 6, c = i & 63;
        fcT[c * D + o] = att_fc[i];
    }
    for (int i = tid; i < H * 10; i += 256)
        w1f[i] = bb_w1[i] * bnS(bb_g1[i / 10]);
    for (int i = tid; i < D * H; i += 256) {
        int o = i >> 6, c = i & 63;                 // att_w is (H rows o, D cols c)
        awT[c * H + o] = att_w[i] * bnS(att_g[o]);
    }
    if (tid < H) { b1f[tid] = bb_b1[tid]; ab[tid] = att_b[tid]; }
    __syncthreads();

    int wid = tid >> 6, lane = tid & 63;
    int p = blockIdx.x * PPB + wid;
    int b = p >> 15, n = p & (NPTS - 1);
    int k = lane >> 2, q = lane & 3;

    int nb = nidx[(p << 4) + k];
    const float* cxp = xyz + (size_t)(b * NPTS + n) * 3;
    const float* nxp = xyz + (size_t)(b * NPTS + nb) * 3;
    float cx0 = cxp[0], cx1 = cxp[1], cx2 = cxp[2];
    float nx0 = nxp[0], nx1 = nxp[1], nx2 = nxp[2];
    float r0 = cx0 - nx0, r1 = cx1 - nx1, r2 = cx2 - nx2;
    float dist = sqrtf(r0 * r0 + r1 * r1 + r2 * r2);
    float in10[10] = {dist, r0, r1, r2, cx0, cx1, cx2, nx0, nx1, nx2};
#pragma unroll
    for (int j = 0; j < 8; ++j) {
        int c = (q << 3) + j;
        float acc = b1f[c];
#pragma unroll
        for (int t = 0; t < 10; ++t) acc += w1f[c * 10 + t] * in10[t];
        feat[wid][H + c][k] = fmaxf(acc, 0.0f);
    }
    {   // f_nb gather from f_pc
        const float4* src = (const float4*)(f_pc + (((size_t)(b * NPTS + nb)) << 5) + (q << 3));
        float4 v0 = src[0], v1 = src[1];
        int c0 = q << 3;
        feat[wid][c0 + 0][k] = v0.x; feat[wid][c0 + 1][k] = v0.y;
        feat[wid][c0 + 2][k] = v0.z; feat[wid][c0 + 3][k] = v0.w;
        feat[wid][c0 + 4][k] = v1.x; feat[wid][c0 + 5][k] = v1.y;
        feat[wid][c0 + 6][k] = v1.z; feat[wid][c0 + 7][k] = v1.w;
    }
    __syncthreads();

    // scores: lane = output channel
    float l[KNB];
#pragma unroll
    for (int kk = 0; kk < KNB; ++kk) l[kk] = 0.0f;
    for (int cp = 0; cp < D; ++cp) {
        float w = fcT[cp * D + lane];
        const float4* row = (const float4*)&feat[wid][cp][0];
        float4 a0 = row[0], a1 = row[1], a2 = row[2], a3 = row[3];
        l[0] += w * a0.x; l[1] += w * a0.y; l[2]  += w * a0.z; l[3]  += w * a0.w;
        l[4] += w * a1.x; l[5] += w * a1.y; l[6]  += w * a1.z; l[7]  += w * a1.w;
        l[8] += w * a2.x; l[9] += w * a2.y; l[10] += w * a2.z; l[11] += w * a2.w;
        l[12]+= w * a3.x; l[13]+= w * a3.y; l[14] += w * a3.z; l[15] += w * a3.w;
    }
    float m = l[0];
#pragma unroll
    for (int kk = 1; kk < KNB; ++kk) m = fmaxf(m, l[kk]);
    float e[KNB]; float s = 0.0f;
#pragma unroll
    for (int kk = 0; kk < KNB; ++kk) { e[kk] = __expf(l[kk] - m); s += e[kk]; }
    float inv = 1.0f / s;
    const float4* myrow = (const float4*)&feat[wid][lane][0];
    float agg = 0.0f;
#pragma unroll
    for (int g4 = 0; g4 < 4; ++g4) {
        float4 a = myrow[g4];
        agg += a.x * e[4 * g4] + a.y * e[4 * g4 + 1] + a.z * e[4 * g4 + 2] + a.w * e[4 * g4 + 3];
    }
    aggbuf[wid][lane] = agg * inv;
    __syncthreads();

    if (lane < H) {
        float acc = ab[lane];
#pragma unroll
        for (int c = 0; c < D; ++c) acc += awT[c * H + lane] * aggbuf[wid][c];
        f_agg[(((size_t)p) << 5) + lane] = fmaxf(acc, 0.0f);
    }
}

// ---------------- Kernel 3: stage-2 building block -> f_agg2 channel-major (B,64,N) ----------------
__global__ __launch_bounds__(256) void k3_stage2(
    const float* __restrict__ xyz, const int* __restrict__ nidx,
    const float* __restrict__ f_agg,
    const float* __restrict__ bb_w1, const float* __restrict__ bb_g1, const float* __restrict__ bb_b1,
    const float* __restrict__ bb_w2, const float* __restrict__ bb_g2, const float* __restrict__ bb_b2,
    const float* __restrict__ att_fc,
    const float* __restrict__ att_w, const float* __restrict__ att_g, const float* __restrict__ att_b,
    float* __restrict__ fagg2T)
{
    __shared__ float fcT[D * D];                    // att2_fc transposed
    __shared__ float w1f[H * 10];
    __shared__ float b1f[H];
    __shared__ float w2T[H * H];                    // bb_w2 transposed, folded
    __shared__ float b2f[H];
    __shared__ float awT[D * D];                    // att2_w transposed, folded
    __shared__ float ab[D];
    __shared__ __align__(16) float feat[PPB][D][20];
    __shared__ float aggbuf[PPB][D];
    __shared__ float stg[PPB][D];

    int tid = threadIdx.x;
    for (int i = tid; i < D * D; i += 256) {
        int o = i >> 6, c = i & 63;
        fcT[c * D + o] = att_fc[i];
        awT[c * D + o] = att_w[i] * bnS(att_g[o]);
    }
    for (int i = tid; i < H * 10; i += 256)
        w1f[i] = bb_w1[i] * bnS(bb_g1[i / 10]);
    for (int i = tid; i < H * H; i += 256) {
        int o = i >> 5, c = i & 31;
        w2T[c * H + o] = bb_w2[i] * bnS(bb_g2[o]);
    }
    if (tid < H) { b1f[tid] = bb_b1[tid]; b2f[tid] = bb_b2[tid]; }
    if (tid < D) ab[tid] = att_b[tid];
    __syncthreads();

    int wid = tid >> 6, lane = tid & 63;
    int p = blockIdx.x * PPB + wid;
    int b = p >> 15, n = p & (NPTS - 1);
    int k = lane >> 2, q = lane & 3;

    int nb = nidx[(p << 4) + k];
    const float* cxp = xyz + (size_t)(b * NPTS + n) * 3;
    const float* nxp = xyz + (size_t)(b * NPTS + nb) * 3;
    float cx0 = cxp[0], cx1 = cxp[1], cx2 = cxp[2];
    float nx0 = nxp[0], nx1 = nxp[1], nx2 = nxp[2];
    float r0 = cx0 - nx0, r1 = cx1 - nx1, r2 = cx2 - nx2;
    float dist = sqrtf(r0 * r0 + r1 * r1 + r2 * r2);
    float in10[10] = {dist, r0, r1, r2, cx0, cx1, cx2, nx0, nx1, nx2};
#pragma unroll
    for (int j = 0; j < 8; ++j) {
        int c = (q << 3) + j;
        float acc = b1f[c];
#pragma unroll
        for (int t = 0; t < 10; ++t) acc += w1f[c * 10 + t] * in10[t];
        feat[wid][H + c][k] = fmaxf(acc, 0.0f);    // stage-1 f_xyz (pre bb_w2)
    }
    {   // f_nb2 gather from f_agg
        const float4* src = (const float4*)(f_agg + (((size_t)(b * NPTS + nb)) << 5) + (q << 3));
        float4 v0 = src[0], v1 = src[1];
        int c0 = q << 3;
        feat[wid][c0 + 0][k] = v0.x; feat[wid][c0 + 1][k] = v0.y;
        feat[wid][c0 + 2][k] = v0.z; feat[wid][c0 + 3][k] = v0.w;
        feat[wid][c0 + 4][k] = v1.x; feat[wid][c0 + 5][k] = v1.y;
        feat[wid][c0 + 6][k] = v1.z; feat[wid][c0 + 7][k] = v1.w;
    }
    __syncthreads();

    // f_xyz2 = relu(bn(bb_w2 @ f_xyz))
    float fx2[8];
#pragma unroll
    for (int j = 0; j < 8; ++j) fx2[j] = b2f[(q << 3) + j];
    for (int cin = 0; cin < H; ++cin) {
        float xv = feat[wid][H + cin][k];
#pragma unroll
        for (int j = 0; j < 8; ++j) fx2[j] += w2T[cin * H + (q << 3) + j] * xv;
    }
    __syncthreads();
#pragma unroll
    for (int j = 0; j < 8; ++j)
        feat[wid][H + (q << 3) + j][k] = fmaxf(fx2[j], 0.0f);
    __syncthreads();

    // scores (att2_fc): lane = output channel
    float l[KNB];
#pragma unroll
    for (int kk = 0; kk < KNB; ++kk) l[kk] = 0.0f;
    for (int cp = 0; cp < D; ++cp) {
        float w = fcT[cp * D + lane];
        const float4* row = (const float4*)&feat[wid][cp][0];
        float4 a0 = row[0], a1 = row[1], a2 = row[2], a3 = row[3];
        l[0] += w * a0.x; l[1] += w * a0.y; l[2]  += w * a0.z; l[3]  += w * a0.w;
        l[4] += w * a1.x; l[5] += w * a1.y; l[6]  += w * a1.z; l[7]  += w * a1.w;
        l[8] += w * a2.x; l[9] += w * a2.y; l[10] += w * a2.z; l[11] += w * a2.w;
        l[12]+= w * a3.x; l[13]+= w * a3.y; l[14] += w * a3.z; l[15] += w * a3.w;
    }
    float m = l[0];
#pragma unroll
    for (int kk = 1; kk < KNB; ++kk) m = fmaxf(m, l[kk]);
    float e[KNB]; float s = 0.0f;
#pragma unroll
    for (int kk = 0; kk < KNB; ++kk) { e[kk] = __expf(l[kk] - m); s += e[kk]; }
    float inv = 1.0f / s;
    const float4* myrow = (const float4*)&feat[wid][lane][0];
    float agg = 0.0f;
#pragma unroll
    for (int g4 = 0; g4 < 4; ++g4) {
        float4 a = myrow[g4];
        agg += a.x * e[4 * g4] + a.y * e[4 * g4 + 1] + a.z * e[4 * g4 + 2] + a.w * e[4 * g4 + 3];
    }
    aggbuf[wid][lane] = agg * inv;
    __syncthreads();

    // f_agg2 = relu(bn(att2_w @ agg2)), all 64 lanes, o = lane
    {
        float acc = ab[lane];
#pragma unroll
        for (int c = 0; c < D; ++c) acc += awT[c * D + lane] * aggbuf[wid][c];
        stg[wid][lane] = fmaxf(acc, 0.0f);
    }
    __syncthreads();

    // cooperative transposed store to channel-major (B,64,N)
    {
        int nn = tid & (PPB - 1), c = tid >> 2;     // PPB==4, 256 threads -> 4x64
        int base = blockIdx.x * PPB;
        int bb = base >> 15, n0 = base & (NPTS - 1);
        fagg2T[((bb * D + c) << 15) + n0 + nn] = stg[nn][c];
    }
}

// ---------------- Kernel 4: out = leaky(bn(mlp2@f_agg2) + bn(sc@feature)) ----------------
__global__ __launch_bounds__(256) void k4_final(
    const float* __restrict__ fagg2T, const float* __restrict__ feature,
    const float* __restrict__ w_mlp2, const float* __restrict__ g_mlp2, const float* __restrict__ b_mlp2,
    const float* __restrict__ w_sc, const float* __restrict__ g_sc, const float* __restrict__ b_sc,
    float* __restrict__ out)
{
    __shared__ __align__(16) float wc[DOUT * 96];   // [o][96]: 64 mlp2 cols then 32 sc cols (bn-folded)
    __shared__ float bc[DOUT];
    int tid = threadIdx.x;
    for (int i = tid; i < DOUT * 96; i += 256) {
        int o = i / 96, c = i - o * 96;
        wc[i] = (c < D) ? w_mlp2[o * D + c] * bnS(g_mlp2[o])
                        : w_sc[o * CIN + (c - D)] * bnS(g_sc[o]);
    }
    if (tid < DOUT) bc[tid] = b_mlp2[tid] + b_sc[tid];
    __syncthreads();

    int wid = tid >> 6, lane = tid & 63;
    int gb = blockIdx.x;                            // 1024 blocks: (b, 512 n-tiles of 64)
    int b = gb >> 9, n = ((gb & 511) << 6) + lane;
    int o0 = wid * 32;

    float acc[32];
#pragma unroll
    for (int j = 0; j < 32; ++j) acc[j] = bc[o0 + j];

    for (int cb = 0; cb < 16; ++cb) {               // c = 0..63 from f_agg2
        float x0 = fagg2T[((b * D + 4 * cb + 0) << 15) + n];
        float x1 = fagg2T[((b * D + 4 * cb + 1) << 15) + n];
        float x2 = fagg2T[((b * D + 4 * cb + 2) << 15) + n];
        float x3 = fagg2T[((b * D + 4 * cb + 3) << 15) + n];
#pragma unroll
        for (int j = 0; j < 32; ++j) {
            const float4 w4 = *(const float4*)&wc[(o0 + j) * 96 + 4 * cb];
            acc[j] += w4.x * x0 + w4.y * x1 + w4.z * x2 + w4.w * x3;
        }
    }
    for (int cb = 0; cb < 8; ++cb) {                // c = 64..95 from feature (shortcut)
        float x0 = feature[((b * CIN + 4 * cb + 0) << 15) + n];
        float x1 = feature[((b * CIN + 4 * cb + 1) << 15) + n];
        float x2 = feature[((b * CIN + 4 * cb + 2) << 15) + n];
        float x3 = feature[((b * CIN + 4 * cb + 3) << 15) + n];
#pragma unroll
        for (int j = 0; j < 32; ++j) {
            const float4 w4 = *(const float4*)&wc[(o0 + j) * 96 + D + 4 * cb];
            acc[j] += w4.x * x0 + w4.y * x1 + w4.z * x2 + w4.w * x3;
        }
    }
#pragma unroll
    for (int j = 0; j < 32; ++j) {
        float v = acc[j];
        v = (v >= 0.0f) ? v : 0.2f * v;
        out[((b * DOUT + o0 + j) << 15) + n] = v;
    }
}

extern "C" void kernel_launch(void* const* d_in, const int* in_sizes, int n_in,
                              void* d_out, int out_size, void* d_ws, size_t ws_size,
                              hipStream_t stream) {
    const float* feature = (const float*)d_in[0];
    const float* xyz     = (const float*)d_in[1];
    const float* w_mlp1  = (const float*)d_in[2];
    const float* g_mlp1  = (const float*)d_in[3];
    const float* b_mlp1  = (const float*)d_in[4];
    const float* bb_w1   = (const float*)d_in[5];
    const float* bb_g1   = (const float*)d_in[6];
    const float* bb_b1   = (const float*)d_in[7];
    const float* att1_fc = (const float*)d_in[8];
    const float* att1_w  = (const float*)d_in[9];
    const float* att1_g  = (const float*)d_in[10];
    const float* att1_b  = (const float*)d_in[11];
    const float* bb_w2   = (const float*)d_in[12];
    const float* bb_g2   = (const float*)d_in[13];
    const float* bb_b2   = (const float*)d_in[14];
    const float* att2_fc = (const float*)d_in[15];
    const float* att2_w  = (const float*)d_in[16];
    const float* att2_g  = (const float*)d_in[17];
    const float* att2_b  = (const float*)d_in[18];
    const float* w_mlp2  = (const float*)d_in[19];
    const float* g_mlp2  = (const float*)d_in[20];
    const float* b_mlp2  = (const float*)d_in[21];
    const float* w_sc    = (const float*)d_in[22];
    const float* g_sc    = (const float*)d_in[23];
    const float* b_sc    = (const float*)d_in[24];
    const int*   nidx    = (const int*)d_in[25];
    float* out = (float*)d_out;

    float* f_pc   = (float*)d_ws;                 // B*N*32 = 2M floats
    float* f_agg  = f_pc + (size_t)NB * NPTS * H; // 2M floats
    float* fagg2T = f_agg + (size_t)NB * NPTS * H;// B*64*N = 4M floats

    k1_mlp1<<<NB * NPTS / 256, 256, 0, stream>>>(feature, w_mlp1, g_mlp1, b_mlp1, f_pc);
    k2_stage1<<<NB * NPTS / PPB, 256, 0, stream>>>(xyz, nidx, f_pc,
                                                   bb_w1, bb_g1, bb_b1,
                                                   att1_fc, att1_w, att1_g, att1_b, f_agg);
    k3_stage2<<<NB * NPTS / PPB, 256, 0, stream>>>(xyz, nidx, f_agg,
                                                   bb_w1, bb_g1, bb_b1,
                                                   bb_w2, bb_g2, bb_b2,
                                                   att2_fc, att2_w, att2_g, att2_b, fagg2T);
    k4_final<<<NB * NPTS / 64, 256, 0, stream>>>(fagg2T, feature,
                                                 w_mlp2, g_mlp2, b_mlp2,
                                                 w_sc, g_sc, b_sc, out);
}

// Round 2
// 853.403 us; speedup vs baseline: 1.1402x; 1.1402x over previous
//
#include <hip/hip_runtime.h>
#include <math.h>

#define NPTS 32768
#define NB 2
#define CIN 32
#define H 32
#define D 64
#define DOUT 128
#define BN_RS 0.99999500003749981f   // 1/sqrt(1 + 1e-5)

// ---------------- Kernel 1: f_pc = relu(bn(w_mlp1 @ feature)) ----------------
// feature: (B,32,N) channel-major. f_pc out: point-major (B*N, 32).
__global__ __launch_bounds__(256) void k1_mlp1(
    const float* __restrict__ feature, const float* __restrict__ w_mlp1,
    const float* __restrict__ g_mlp1, const float* __restrict__ b_mlp1,
    float* __restrict__ f_pc)
{
    int tid = threadIdx.x;
    int pg = blockIdx.x * 256 + tid;
    int b = pg >> 15, n = pg & (NPTS - 1);

    float x[CIN];
#pragma unroll
    for (int c = 0; c < CIN; ++c)
        x[c] = feature[((b * CIN + c) << 15) + n];

    float outv[CIN];
#pragma unroll
    for (int o = 0; o < CIN; ++o) {
        float s0 = 0.f, s1 = 0.f, s2 = 0.f, s3 = 0.f;
        const float* w = w_mlp1 + o * CIN;   // wave-uniform -> s_load
#pragma unroll
        for (int c = 0; c < CIN; c += 4) {
            s0 = fmaf(w[c + 0], x[c + 0], s0);
            s1 = fmaf(w[c + 1], x[c + 1], s1);
            s2 = fmaf(w[c + 2], x[c + 2], s2);
            s3 = fmaf(w[c + 3], x[c + 3], s3);
        }
        float acc = (s0 + s1) + (s2 + s3);
        outv[o] = fmaxf(fmaf(acc, g_mlp1[o] * BN_RS, b_mlp1[o]), 0.f);
    }
    float4* dst = (float4*)(f_pc + ((size_t)pg << 5));
#pragma unroll
    for (int j = 0; j < CIN / 4; ++j)
        dst[j] = make_float4(outv[4 * j], outv[4 * j + 1], outv[4 * j + 2], outv[4 * j + 3]);
}

// ---------------- Kernel 2: stage-1 building block -> f_agg (B*N, 32) ----------------
// 256 thr = 4 waves; wave = 4 points x 16 neighbors. Block = 16 points.
__global__ __launch_bounds__(256) void k2_stage1(
    const float* __restrict__ xyz, const int* __restrict__ nidx,
    const float* __restrict__ f_pc,
    const float* __restrict__ bb_w1, const float* __restrict__ bb_g1, const float* __restrict__ bb_b1,
    const float* __restrict__ att_fc,
    const float* __restrict__ att_w, const float* __restrict__ att_g, const float* __restrict__ att_b,
    float* __restrict__ f_agg)
{
    __shared__ float awT[D * H];          // folded att_w^T: [c][o]
    __shared__ float aggb[16][D + 1];     // per-point pooled features

    int tid = threadIdx.x;
    for (int i = tid; i < D * H; i += 256) {
        int o = i & (H - 1), c = i >> 5;
        awT[i] = att_w[o * D + c] * (att_g[o] * BN_RS);
    }
    __syncthreads();

    int wid = tid >> 6, lane = tid & 63;
    int p4 = lane >> 4, kk = lane & 15;
    int pt = (wid << 2) + p4;
    int p = (blockIdx.x << 4) + pt;
    int b = p >> 15, n = p & (NPTS - 1);

    int nb = nidx[((size_t)p << 4) + kk];

    const float* cx = xyz + (size_t)(b * NPTS + n) * 3;
    const float* nx = xyz + (size_t)(b * NPTS + nb) * 3;
    float c0 = cx[0], c1 = cx[1], c2 = cx[2];
    float x0 = nx[0], x1 = nx[1], x2 = nx[2];
    float r0 = c0 - x0, r1 = c1 - x1, r2 = c2 - x2;
    float dist = sqrtf(r0 * r0 + r1 * r1 + r2 * r2);
    float in10[10] = {dist, r0, r1, r2, c0, c1, c2, x0, x1, x2};

    float feat[D];
    {   // f_nb gather (channels 0..31)
        const float4* src = (const float4*)(f_pc + (((size_t)(b * NPTS + nb)) << 5));
#pragma unroll
        for (int j = 0; j < 8; ++j) {
            float4 v = src[j];
            feat[4 * j + 0] = v.x; feat[4 * j + 1] = v.y;
            feat[4 * j + 2] = v.z; feat[4 * j + 3] = v.w;
        }
    }
#pragma unroll
    for (int c = 0; c < H; ++c) {         // f_xyz (channels 32..63)
        float a = 0.f;
        const float* w = bb_w1 + c * 10;  // uniform -> s_load
#pragma unroll
        for (int t = 0; t < 10; ++t) a = fmaf(w[t], in10[t], a);
        feat[H + c] = fmaxf(fmaf(a, bb_g1[c] * BN_RS, bb_b1[c]), 0.f);
    }

    // scores conv + softmax-over-k + pool, fused per output channel o
#pragma unroll
    for (int o = 0; o < D; ++o) {
        float s0 = 0.f, s1 = 0.f, s2 = 0.f, s3 = 0.f;
        const float* w = att_fc + o * D;  // uniform -> s_load
#pragma unroll
        for (int c = 0; c < D; c += 4) {
            s0 = fmaf(w[c + 0], feat[c + 0], s0);
            s1 = fmaf(w[c + 1], feat[c + 1], s1);
            s2 = fmaf(w[c + 2], feat[c + 2], s2);
            s3 = fmaf(w[c + 3], feat[c + 3], s3);
        }
        float e = __expf((s0 + s1) + (s2 + s3));   // logits small: no max-sub needed
        float pe = feat[o] * e;
#pragma unroll
        for (int m = 1; m <= 8; m <<= 1) {
            e  += __shfl_xor(e, m);
            pe += __shfl_xor(pe, m);
        }
        if (kk == (o & 15)) aggb[pt][o] = __fdividef(pe, e);
    }

    // output MLP: lane kk computes o = 2kk, 2kk+1
    float a00 = 0.f, a01 = 0.f, a10 = 0.f, a11 = 0.f;
#pragma unroll
    for (int c = 0; c < D; c += 2) {
        float xv0 = aggb[pt][c], xv1 = aggb[pt][c + 1];
        float2 w0 = ((const float2*)awT)[c * (H / 2) + kk];
        float2 w1 = ((const float2*)awT)[(c + 1) * (H / 2) + kk];
        a00 = fmaf(w0.x, xv0, a00); a01 = fmaf(w0.y, xv0, a01);
        a10 = fmaf(w1.x, xv1, a10); a11 = fmaf(w1.y, xv1, a11);
    }
    float2 bb = ((const float2*)att_b)[kk];
    float v0 = fmaxf(a00 + a10 + bb.x, 0.f);
    float v1 = fmaxf(a01 + a11 + bb.y, 0.f);
    ((float2*)(f_agg + ((size_t)p << 5)))[kk] = make_float2(v0, v1);
}

// ---------------- Kernel 3: stage-2 building block -> f_agg2 point-major (B*N, 64) ----------------
__global__ __launch_bounds__(256) void k3_stage2(
    const float* __restrict__ xyz, const int* __restrict__ nidx,
    const float* __restrict__ f_agg,
    const float* __restrict__ bb_w1, const float* __restrict__ bb_g1, const float* __restrict__ bb_b1,
    const float* __restrict__ bb_w2, const float* __restrict__ bb_g2, const float* __restrict__ bb_b2,
    const float* __restrict__ att_fc,
    const float* __restrict__ att_w, const float* __restrict__ att_g, const float* __restrict__ att_b,
    float* __restrict__ fagg2)
{
    __shared__ float awT[D * D];          // folded att2_w^T: [c][o]
    __shared__ float aggb[16][D + 1];

    int tid = threadIdx.x;
    for (int i = tid; i < D * D; i += 256) {
        int o = i & (D - 1), c = i >> 6;
        awT[i] = att_w[o * D + c] * (att_g[o] * BN_RS);
    }
    __syncthreads();

    int wid = tid >> 6, lane = tid & 63;
    int p4 = lane >> 4, kk = lane & 15;
    int pt = (wid << 2) + p4;
    int p = (blockIdx.x << 4) + pt;
    int b = p >> 15, n = p & (NPTS - 1);

    int nb = nidx[((size_t)p << 4) + kk];

    const float* cx = xyz + (size_t)(b * NPTS + n) * 3;
    const float* nx = xyz + (size_t)(b * NPTS + nb) * 3;
    float c0 = cx[0], c1 = cx[1], c2 = cx[2];
    float x0 = nx[0], x1 = nx[1], x2 = nx[2];
    float r0 = c0 - x0, r1 = c1 - x1, r2 = c2 - x2;
    float dist = sqrtf(r0 * r0 + r1 * r1 + r2 * r2);
    float in10[10] = {dist, r0, r1, r2, c0, c1, c2, x0, x1, x2};

    // stage-1 f_xyz (recomputed, cheap)
    float fx[H];
#pragma unroll
    for (int c = 0; c < H; ++c) {
        float a = 0.f;
        const float* w = bb_w1 + c * 10;
#pragma unroll
        for (int t = 0; t < 10; ++t) a = fmaf(w[t], in10[t], a);
        fx[c] = fmaxf(fmaf(a, bb_g1[c] * BN_RS, bb_b1[c]), 0.f);
    }

    float feat[D];
    {   // f_nb2 gather from f_agg (channels 0..31)
        const float4* src = (const float4*)(f_agg + (((size_t)(b * NPTS + nb)) << 5));
#pragma unroll
        for (int j = 0; j < 8; ++j) {
            float4 v = src[j];
            feat[4 * j + 0] = v.x; feat[4 * j + 1] = v.y;
            feat[4 * j + 2] = v.z; feat[4 * j + 3] = v.w;
        }
    }
    // f_xyz2 = relu(bn(bb_w2 @ fx)) (channels 32..63)
#pragma unroll
    for (int j = 0; j < H; ++j) {
        float s0 = 0.f, s1 = 0.f, s2 = 0.f, s3 = 0.f;
        const float* w = bb_w2 + j * H;
#pragma unroll
        for (int c = 0; c < H; c += 4) {
            s0 = fmaf(w[c + 0], fx[c + 0], s0);
            s1 = fmaf(w[c + 1], fx[c + 1], s1);
            s2 = fmaf(w[c + 2], fx[c + 2], s2);
            s3 = fmaf(w[c + 3], fx[c + 3], s3);
        }
        float a = (s0 + s1) + (s2 + s3);
        feat[H + j] = fmaxf(fmaf(a, bb_g2[j] * BN_RS, bb_b2[j]), 0.f);
    }

    // scores conv (att2_fc) + softmax + pool
#pragma unroll
    for (int o = 0; o < D; ++o) {
        float s0 = 0.f, s1 = 0.f, s2 = 0.f, s3 = 0.f;
        const float* w = att_fc + o * D;
#pragma unroll
        for (int c = 0; c < D; c += 4) {
            s0 = fmaf(w[c + 0], feat[c + 0], s0);
            s1 = fmaf(w[c + 1], feat[c + 1], s1);
            s2 = fmaf(w[c + 2], feat[c + 2], s2);
            s3 = fmaf(w[c + 3], feat[c + 3], s3);
        }
        float e = __expf((s0 + s1) + (s2 + s3));
        float pe = feat[o] * e;
#pragma unroll
        for (int m = 1; m <= 8; m <<= 1) {
            e  += __shfl_xor(e, m);
            pe += __shfl_xor(pe, m);
        }
        if (kk == (o & 15)) aggb[pt][o] = __fdividef(pe, e);
    }

    // output MLP: lane kk computes o = 4kk..4kk+3
    float a0 = 0.f, a1 = 0.f, a2 = 0.f, a3 = 0.f;
#pragma unroll
    for (int c = 0; c < D; ++c) {
        float xv = aggb[pt][c];
        float4 w4 = ((const float4*)awT)[c * (D / 4) + kk];
        a0 = fmaf(w4.x, xv, a0); a1 = fmaf(w4.y, xv, a1);
        a2 = fmaf(w4.z, xv, a2); a3 = fmaf(w4.w, xv, a3);
    }
    float4 bb = ((const float4*)att_b)[kk];
    float4 r;
    r.x = fmaxf(a0 + bb.x, 0.f);
    r.y = fmaxf(a1 + bb.y, 0.f);
    r.z = fmaxf(a2 + bb.z, 0.f);
    r.w = fmaxf(a3 + bb.w, 0.f);
    ((float4*)(fagg2 + ((size_t)p << 6)))[kk] = r;
}

// ---------------- Kernel 4: out = leaky(bn(mlp2@f_agg2) + bn(sc@feature)) ----------------
// Block = 64 points (n-tile), 4 waves each owning a 32-output quarter.
__global__ __launch_bounds__(256) void k4_final(
    const float* __restrict__ fagg2, const float* __restrict__ feature,
    const float* __restrict__ w_mlp2, const float* __restrict__ g_mlp2, const float* __restrict__ b_mlp2,
    const float* __restrict__ w_sc, const float* __restrict__ g_sc, const float* __restrict__ b_sc,
    float* __restrict__ out)
{
    __shared__ float tile[64][D + 1];
    int tid = threadIdx.x;
    int gb = blockIdx.x;
    int b = gb >> 9, n0 = (gb & 511) << 6;

    {   // stage 64 points x 64 ch, coalesced
        const float4* src = (const float4*)(fagg2 + (((size_t)(b * NPTS + n0)) << 6));
        for (int i = tid; i < 64 * 16; i += 256) {
            float4 v = src[i];
            int ptl = i >> 4, c4 = (i & 15) << 2;
            tile[ptl][c4 + 0] = v.x; tile[ptl][c4 + 1] = v.y;
            tile[ptl][c4 + 2] = v.z; tile[ptl][c4 + 3] = v.w;
        }
    }
    __syncthreads();

    int wid = tid >> 6, lane = tid & 63;
    int n = n0 + lane;
    int o0 = wid * 32;

    float xr[D];
#pragma unroll 8
    for (int c = 0; c < D; ++c) xr[c] = tile[lane][c];
    float xf[CIN];
#pragma unroll
    for (int c = 0; c < CIN; ++c) xf[c] = feature[((b * CIN + c) << 15) + n];

#pragma unroll
    for (int j = 0; j < 32; ++j) {
        int o = o0 + j;
        float s0 = 0.f, s1 = 0.f, s2 = 0.f, s3 = 0.f;
        const float* wm = w_mlp2 + o * D;   // uniform -> s_load
#pragma unroll
        for (int c = 0; c < D; c += 4) {
            s0 = fmaf(wm[c + 0], xr[c + 0], s0);
            s1 = fmaf(wm[c + 1], xr[c + 1], s1);
            s2 = fmaf(wm[c + 2], xr[c + 2], s2);
            s3 = fmaf(wm[c + 3], xr[c + 3], s3);
        }
        float aA = (s0 + s1) + (s2 + s3);
        float t0 = 0.f, t1 = 0.f, t2 = 0.f, t3 = 0.f;
        const float* ws = w_sc + o * CIN;
#pragma unroll
        for (int c = 0; c < CIN; c += 4) {
            t0 = fmaf(ws[c + 0], xf[c + 0], t0);
            t1 = fmaf(ws[c + 1], xf[c + 1], t1);
            t2 = fmaf(ws[c + 2], xf[c + 2], t2);
            t3 = fmaf(ws[c + 3], xf[c + 3], t3);
        }
        float aB = (t0 + t1) + (t2 + t3);
        float v = fmaf(aA, g_mlp2[o] * BN_RS, b_mlp2[o])
                + fmaf(aB, g_sc[o] * BN_RS, b_sc[o]);
        v = (v >= 0.0f) ? v : 0.2f * v;
        out[((b * DOUT + o) << 15) + n] = v;
    }
}

extern "C" void kernel_launch(void* const* d_in, const int* in_sizes, int n_in,
                              void* d_out, int out_size, void* d_ws, size_t ws_size,
                              hipStream_t stream) {
    const float* feature = (const float*)d_in[0];
    const float* xyz     = (const float*)d_in[1];
    const float* w_mlp1  = (const float*)d_in[2];
    const float* g_mlp1  = (const float*)d_in[3];
    const float* b_mlp1  = (const float*)d_in[4];
    const float* bb_w1   = (const float*)d_in[5];
    const float* bb_g1   = (const float*)d_in[6];
    const float* bb_b1   = (const float*)d_in[7];
    const float* att1_fc = (const float*)d_in[8];
    const float* att1_w  = (const float*)d_in[9];
    const float* att1_g  = (const float*)d_in[10];
    const float* att1_b  = (const float*)d_in[11];
    const float* bb_w2   = (const float*)d_in[12];
    const float* bb_g2   = (const float*)d_in[13];
    const float* bb_b2   = (const float*)d_in[14];
    const float* att2_fc = (const float*)d_in[15];
    const float* att2_w  = (const float*)d_in[16];
    const float* att2_g  = (const float*)d_in[17];
    const float* att2_b  = (const float*)d_in[18];
    const float* w_mlp2  = (const float*)d_in[19];
    const float* g_mlp2  = (const float*)d_in[20];
    const float* b_mlp2  = (const float*)d_in[21];
    const float* w_sc    = (const float*)d_in[22];
    const float* g_sc    = (const float*)d_in[23];
    const float* b_sc    = (const float*)d_in[24];
    const int*   nidx    = (const int*)d_in[25];
    float* out = (float*)d_out;

    float* f_pc  = (float*)d_ws;                   // B*N*32
    float* f_agg = f_pc + (size_t)NB * NPTS * H;   // B*N*32
    float* fagg2 = f_agg + (size_t)NB * NPTS * H;  // B*N*64 point-major

    k1_mlp1<<<NB * NPTS / 256, 256, 0, stream>>>(feature, w_mlp1, g_mlp1, b_mlp1, f_pc);
    k2_stage1<<<NB * NPTS / 16, 256, 0, stream>>>(xyz, nidx, f_pc,
                                                  bb_w1, bb_g1, bb_b1,
                                                  att1_fc, att1_w, att1_g, att1_b, f_agg);
    k3_stage2<<<NB * NPTS / 16, 256, 0, stream>>>(xyz, nidx, f_agg,
                                                  bb_w1, bb_g1, bb_b1,
                                                  bb_w2, bb_g2, bb_b2,
                                                  att2_fc, att2_w, att2_g, att2_b, fagg2);
    k4_final<<<NB * NPTS / 64, 256, 0, stream>>>(fagg2, feature,
                                                 w_mlp2, g_mlp2, b_mlp2,
                                                 w_sc, g_sc, b_sc, out);
}

// Round 3
// 564.414 us; speedup vs baseline: 1.7240x; 1.5120x over previous
//
#include <hip/hip_runtime.h>
#include <math.h>

#define NPTS 32768
#define NB 2
#define CIN 32
#define H 32
#define D 64
#define DOUT 128
#define BN_RS 0.99999500003749981f   // 1/sqrt(1 + 1e-5)

// ---------------- Kernel 1: f_pc = relu(bn(w_mlp1 @ feature)) ----------------
// feature: (B,32,N) channel-major. f_pc out: point-major (B*N, 32).
__global__ __launch_bounds__(256) void k1_mlp1(
    const float* __restrict__ feature, const float* __restrict__ w_mlp1,
    const float* __restrict__ g_mlp1, const float* __restrict__ b_mlp1,
    float* __restrict__ f_pc)
{
    int tid = threadIdx.x;
    int pg = blockIdx.x * 256 + tid;
    int b = pg >> 15, n = pg & (NPTS - 1);

    float x[CIN];
#pragma unroll
    for (int c = 0; c < CIN; ++c)
        x[c] = feature[((b * CIN + c) << 15) + n];

    float outv[CIN];
#pragma unroll
    for (int o = 0; o < CIN; ++o) {
        float s0 = 0.f, s1 = 0.f, s2 = 0.f, s3 = 0.f;
        const float* w = w_mlp1 + o * CIN;   // uniform -> s_load
#pragma unroll
        for (int c = 0; c < CIN; c += 4) {
            s0 = fmaf(w[c + 0], x[c + 0], s0);
            s1 = fmaf(w[c + 1], x[c + 1], s1);
            s2 = fmaf(w[c + 2], x[c + 2], s2);
            s3 = fmaf(w[c + 3], x[c + 3], s3);
        }
        float acc = (s0 + s1) + (s2 + s3);
        outv[o] = fmaxf(fmaf(acc, g_mlp1[o] * BN_RS, b_mlp1[o]), 0.f);
    }
    float4* dst = (float4*)(f_pc + ((size_t)pg << 5));
#pragma unroll
    for (int j = 0; j < CIN / 4; ++j)
        dst[j] = make_float4(outv[4 * j], outv[4 * j + 1], outv[4 * j + 2], outv[4 * j + 3]);
}

// ---------------- Kernel 2: stage-1 building block -> f_agg (B*N, 32) ----------------
// 256 thr = 4 waves; wave = 4 points x 16 neighbors. Block = 16 points.
__global__ __launch_bounds__(256) void k2_stage1(
    const float* __restrict__ xyz, const int* __restrict__ nidx,
    const float* __restrict__ f_pc,
    const float* __restrict__ bb_w1, const float* __restrict__ bb_g1, const float* __restrict__ bb_b1,
    const float* __restrict__ att_fc,
    const float* __restrict__ att_w, const float* __restrict__ att_g, const float* __restrict__ att_b,
    float* __restrict__ f_agg)
{
    __shared__ float awT[D * H];          // folded att_w^T: [c][o]
    __shared__ float aggb[16][D + 1];     // per-point pooled features

    int tid = threadIdx.x;
    for (int i = tid; i < D * H; i += 256) {
        int o = i & (H - 1), c = i >> 5;
        awT[i] = att_w[o * D + c] * (att_g[o] * BN_RS);
    }
    __syncthreads();

    int wid = tid >> 6, lane = tid & 63;
    int p4 = lane >> 4, kk = lane & 15;
    int pt = (wid << 2) + p4;
    int p = (blockIdx.x << 4) + pt;
    int b = p >> 15, n = p & (NPTS - 1);

    int nb = nidx[((size_t)p << 4) + kk];

    const float* cx = xyz + (size_t)(b * NPTS + n) * 3;
    const float* nx = xyz + (size_t)(b * NPTS + nb) * 3;
    float c0 = cx[0], c1 = cx[1], c2 = cx[2];
    float x0 = nx[0], x1 = nx[1], x2 = nx[2];
    float r0 = c0 - x0, r1 = c1 - x1, r2 = c2 - x2;
    float dist = sqrtf(r0 * r0 + r1 * r1 + r2 * r2);
    float in10[10] = {dist, r0, r1, r2, c0, c1, c2, x0, x1, x2};

    float feat[D];
    {   // f_nb gather (channels 0..31)
        const float4* src = (const float4*)(f_pc + (((size_t)(b * NPTS + nb)) << 5));
#pragma unroll
        for (int j = 0; j < 8; ++j) {
            float4 v = src[j];
            feat[4 * j + 0] = v.x; feat[4 * j + 1] = v.y;
            feat[4 * j + 2] = v.z; feat[4 * j + 3] = v.w;
        }
    }
#pragma unroll
    for (int c = 0; c < H; ++c) {         // f_xyz (channels 32..63)
        float a = 0.f;
        const float* w = bb_w1 + c * 10;  // uniform -> s_load
#pragma unroll
        for (int t = 0; t < 10; ++t) a = fmaf(w[t], in10[t], a);
        feat[H + c] = fmaxf(fmaf(a, bb_g1[c] * BN_RS, bb_b1[c]), 0.f);
    }

    // scores conv + softmax-over-k + pool, fused per output channel o
#pragma unroll
    for (int o = 0; o < D; ++o) {
        float s0 = 0.f, s1 = 0.f, s2 = 0.f, s3 = 0.f;
        const float* w = att_fc + o * D;  // uniform -> s_load
#pragma unroll
        for (int c = 0; c < D; c += 4) {
            s0 = fmaf(w[c + 0], feat[c + 0], s0);
            s1 = fmaf(w[c + 1], feat[c + 1], s1);
            s2 = fmaf(w[c + 2], feat[c + 2], s2);
            s3 = fmaf(w[c + 3], feat[c + 3], s3);
        }
        float e = __expf((s0 + s1) + (s2 + s3));   // logits small: no max-sub needed
        float pe = feat[o] * e;
#pragma unroll
        for (int m = 1; m <= 8; m <<= 1) {
            e  += __shfl_xor(e, m);
            pe += __shfl_xor(pe, m);
        }
        if (kk == (o & 15)) aggb[pt][o] = __fdividef(pe, e);
    }

    // output MLP: lane kk computes o = 2kk, 2kk+1
    float a00 = 0.f, a01 = 0.f, a10 = 0.f, a11 = 0.f;
#pragma unroll
    for (int c = 0; c < D; c += 2) {
        float xv0 = aggb[pt][c], xv1 = aggb[pt][c + 1];
        float2 w0 = ((const float2*)awT)[c * (H / 2) + kk];
        float2 w1 = ((const float2*)awT)[(c + 1) * (H / 2) + kk];
        a00 = fmaf(w0.x, xv0, a00); a01 = fmaf(w0.y, xv0, a01);
        a10 = fmaf(w1.x, xv1, a10); a11 = fmaf(w1.y, xv1, a11);
    }
    float2 bb = ((const float2*)att_b)[kk];
    float v0 = fmaxf(a00 + a10 + bb.x, 0.f);
    float v1 = fmaxf(a01 + a11 + bb.y, 0.f);
    ((float2*)(f_agg + ((size_t)p << 5)))[kk] = make_float2(v0, v1);
}

// ---------------- Kernel 3: stage-2 building block -> f_agg2 point-major (B*N, 64) ----------------
__global__ __launch_bounds__(256) void k3_stage2(
    const float* __restrict__ xyz, const int* __restrict__ nidx,
    const float* __restrict__ f_agg,
    const float* __restrict__ bb_w1, const float* __restrict__ bb_g1, const float* __restrict__ bb_b1,
    const float* __restrict__ bb_w2, const float* __restrict__ bb_g2, const float* __restrict__ bb_b2,
    const float* __restrict__ att_fc,
    const float* __restrict__ att_w, const float* __restrict__ att_g, const float* __restrict__ att_b,
    float* __restrict__ fagg2)
{
    __shared__ float awT[D * D];          // folded att2_w^T: [c][o]
    __shared__ float aggb[16][D + 1];

    int tid = threadIdx.x;
    for (int i = tid; i < D * D; i += 256) {
        int o = i & (D - 1), c = i >> 6;
        awT[i] = att_w[o * D + c] * (att_g[o] * BN_RS);
    }
    __syncthreads();

    int wid = tid >> 6, lane = tid & 63;
    int p4 = lane >> 4, kk = lane & 15;
    int pt = (wid << 2) + p4;
    int p = (blockIdx.x << 4) + pt;
    int b = p >> 15, n = p & (NPTS - 1);

    int nb = nidx[((size_t)p << 4) + kk];

    const float* cx = xyz + (size_t)(b * NPTS + n) * 3;
    const float* nx = xyz + (size_t)(b * NPTS + nb) * 3;
    float c0 = cx[0], c1 = cx[1], c2 = cx[2];
    float x0 = nx[0], x1 = nx[1], x2 = nx[2];
    float r0 = c0 - x0, r1 = c1 - x1, r2 = c2 - x2;
    float dist = sqrtf(r0 * r0 + r1 * r1 + r2 * r2);
    float in10[10] = {dist, r0, r1, r2, c0, c1, c2, x0, x1, x2};

    // stage-1 f_xyz (recomputed, cheap)
    float fx[H];
#pragma unroll
    for (int c = 0; c < H; ++c) {
        float a = 0.f;
        const float* w = bb_w1 + c * 10;
#pragma unroll
        for (int t = 0; t < 10; ++t) a = fmaf(w[t], in10[t], a);
        fx[c] = fmaxf(fmaf(a, bb_g1[c] * BN_RS, bb_b1[c]), 0.f);
    }

    float feat[D];
    {   // f_nb2 gather from f_agg (channels 0..31)
        const float4* src = (const float4*)(f_agg + (((size_t)(b * NPTS + nb)) << 5));
#pragma unroll
        for (int j = 0; j < 8; ++j) {
            float4 v = src[j];
            feat[4 * j + 0] = v.x; feat[4 * j + 1] = v.y;
            feat[4 * j + 2] = v.z; feat[4 * j + 3] = v.w;
        }
    }
    // f_xyz2 = relu(bn(bb_w2 @ fx)) (channels 32..63)
#pragma unroll
    for (int j = 0; j < H; ++j) {
        float s0 = 0.f, s1 = 0.f, s2 = 0.f, s3 = 0.f;
        const float* w = bb_w2 + j * H;
#pragma unroll
        for (int c = 0; c < H; c += 4) {
            s0 = fmaf(w[c + 0], fx[c + 0], s0);
            s1 = fmaf(w[c + 1], fx[c + 1], s1);
            s2 = fmaf(w[c + 2], fx[c + 2], s2);
            s3 = fmaf(w[c + 3], fx[c + 3], s3);
        }
        float a = (s0 + s1) + (s2 + s3);
        feat[H + j] = fmaxf(fmaf(a, bb_g2[j] * BN_RS, bb_b2[j]), 0.f);
    }

    // scores conv (att2_fc) + softmax + pool
#pragma unroll
    for (int o = 0; o < D; ++o) {
        float s0 = 0.f, s1 = 0.f, s2 = 0.f, s3 = 0.f;
        const float* w = att_fc + o * D;
#pragma unroll
        for (int c = 0; c < D; c += 4) {
            s0 = fmaf(w[c + 0], feat[c + 0], s0);
            s1 = fmaf(w[c + 1], feat[c + 1], s1);
            s2 = fmaf(w[c + 2], feat[c + 2], s2);
            s3 = fmaf(w[c + 3], feat[c + 3], s3);
        }
        float e = __expf((s0 + s1) + (s2 + s3));
        float pe = feat[o] * e;
#pragma unroll
        for (int m = 1; m <= 8; m <<= 1) {
            e  += __shfl_xor(e, m);
            pe += __shfl_xor(pe, m);
        }
        if (kk == (o & 15)) aggb[pt][o] = __fdividef(pe, e);
    }

    // output MLP: lane kk computes o = 4kk..4kk+3
    float a0 = 0.f, a1 = 0.f, a2 = 0.f, a3 = 0.f;
#pragma unroll
    for (int c = 0; c < D; ++c) {
        float xv = aggb[pt][c];
        float4 w4 = ((const float4*)awT)[c * (D / 4) + kk];
        a0 = fmaf(w4.x, xv, a0); a1 = fmaf(w4.y, xv, a1);
        a2 = fmaf(w4.z, xv, a2); a3 = fmaf(w4.w, xv, a3);
    }
    float4 bb = ((const float4*)att_b)[kk];
    float4 r;
    r.x = fmaxf(a0 + bb.x, 0.f);
    r.y = fmaxf(a1 + bb.y, 0.f);
    r.z = fmaxf(a2 + bb.z, 0.f);
    r.w = fmaxf(a3 + bb.w, 0.f);
    ((float4*)(fagg2 + ((size_t)p << 6)))[kk] = r;
}

// ---------------- Kernel 4: out = leaky(bn(mlp2@f_agg2) + bn(sc@feature)) ----------------
// Grid = 1024 blocks: (256 point-tiles of 256 pts) x (4 output-quarters).
// Thread = one point; o depends only on blockIdx + loop counter -> s_load weights.
__global__ __launch_bounds__(256) void k4_final(
    const float* __restrict__ fagg2, const float* __restrict__ feature,
    const float* __restrict__ w_mlp2, const float* __restrict__ g_mlp2, const float* __restrict__ b_mlp2,
    const float* __restrict__ w_sc, const float* __restrict__ g_sc, const float* __restrict__ b_sc,
    float* __restrict__ out)
{
    int tid = threadIdx.x;
    int gb = blockIdx.x;
    int o0 = (gb & 3) << 5;                 // 0,32,64,96 — uniform (SGPR)
    int p  = ((gb >> 2) << 8) + tid;
    int b = p >> 15, n = p & (NPTS - 1);

    float xr[D];
    {
        const float4* src = (const float4*)(fagg2 + ((size_t)p << 6));
#pragma unroll
        for (int j = 0; j < D / 4; ++j) {
            float4 v = src[j];
            xr[4 * j + 0] = v.x; xr[4 * j + 1] = v.y;
            xr[4 * j + 2] = v.z; xr[4 * j + 3] = v.w;
        }
    }
    float xf[CIN];
#pragma unroll
    for (int c = 0; c < CIN; ++c)
        xf[c] = feature[((b * CIN + c) << 15) + n];

#pragma unroll 4
    for (int j = 0; j < 32; ++j) {
        int o = o0 + j;                     // uniform -> s_load weight rows
        float s0 = 0.f, s1 = 0.f, s2 = 0.f, s3 = 0.f;
        const float* wm = w_mlp2 + o * D;
#pragma unroll
        for (int c = 0; c < D; c += 4) {
            s0 = fmaf(wm[c + 0], xr[c + 0], s0);
            s1 = fmaf(wm[c + 1], xr[c + 1], s1);
            s2 = fmaf(wm[c + 2], xr[c + 2], s2);
            s3 = fmaf(wm[c + 3], xr[c + 3], s3);
        }
        float aA = (s0 + s1) + (s2 + s3);
        float t0 = 0.f, t1 = 0.f, t2 = 0.f, t3 = 0.f;
        const float* ws = w_sc + o * CIN;
#pragma unroll
        for (int c = 0; c < CIN; c += 4) {
            t0 = fmaf(ws[c + 0], xf[c + 0], t0);
            t1 = fmaf(ws[c + 1], xf[c + 1], t1);
            t2 = fmaf(ws[c + 2], xf[c + 2], t2);
            t3 = fmaf(ws[c + 3], xf[c + 3], t3);
        }
        float aB = (t0 + t1) + (t2 + t3);
        float v = fmaf(aA, g_mlp2[o] * BN_RS, b_mlp2[o])
                + fmaf(aB, g_sc[o] * BN_RS, b_sc[o]);
        v = (v >= 0.0f) ? v : 0.2f * v;
        out[((b * DOUT + o) << 15) + n] = v;
    }
}

extern "C" void kernel_launch(void* const* d_in, const int* in_sizes, int n_in,
                              void* d_out, int out_size, void* d_ws, size_t ws_size,
                              hipStream_t stream) {
    const float* feature = (const float*)d_in[0];
    const float* xyz     = (const float*)d_in[1];
    const float* w_mlp1  = (const float*)d_in[2];
    const float* g_mlp1  = (const float*)d_in[3];
    const float* b_mlp1  = (const float*)d_in[4];
    const float* bb_w1   = (const float*)d_in[5];
    const float* bb_g1   = (const float*)d_in[6];
    const float* bb_b1   = (const float*)d_in[7];
    const float* att1_fc = (const float*)d_in[8];
    const float* att1_w  = (const float*)d_in[9];
    const float* att1_g  = (const float*)d_in[10];
    const float* att1_b  = (const float*)d_in[11];
    const float* bb_w2   = (const float*)d_in[12];
    const float* bb_g2   = (const float*)d_in[13];
    const float* bb_b2   = (const float*)d_in[14];
    const float* att2_fc = (const float*)d_in[15];
    const float* att2_w  = (const float*)d_in[16];
    const float* att2_g  = (const float*)d_in[17];
    const float* att2_b  = (const float*)d_in[18];
    const float* w_mlp2  = (const float*)d_in[19];
    const float* g_mlp2  = (const float*)d_in[20];
    const float* b_mlp2  = (const float*)d_in[21];
    const float* w_sc    = (const float*)d_in[22];
    const float* g_sc    = (const float*)d_in[23];
    const float* b_sc    = (const float*)d_in[24];
    const int*   nidx    = (const int*)d_in[25];
    float* out = (float*)d_out;

    float* f_pc  = (float*)d_ws;                   // B*N*32
    float* f_agg = f_pc + (size_t)NB * NPTS * H;   // B*N*32
    float* fagg2 = f_agg + (size_t)NB * NPTS * H;  // B*N*64 point-major

    k1_mlp1<<<NB * NPTS / 256, 256, 0, stream>>>(feature, w_mlp1, g_mlp1, b_mlp1, f_pc);
    k2_stage1<<<NB * NPTS / 16, 256, 0, stream>>>(xyz, nidx, f_pc,
                                                  bb_w1, bb_g1, bb_b1,
                                                  att1_fc, att1_w, att1_g, att1_b, f_agg);
    k3_stage2<<<NB * NPTS / 16, 256, 0, stream>>>(xyz, nidx, f_agg,
                                                  bb_w1, bb_g1, bb_b1,
                                                  bb_w2, bb_g2, bb_b2,
                                                  att2_fc, att2_w, att2_g, att2_b, fagg2);
    k4_final<<<NB * NPTS * 4 / 256, 256, 0, stream>>>(fagg2, feature,
                                                      w_mlp2, g_mlp2, b_mlp2,
                                                      w_sc, g_sc, b_sc, out);
}